// Round 1
// baseline (3943.693 us; speedup 1.0000x reference)
//
#include <hip/hip_runtime.h>

__device__ __forceinline__ float lrelu(float x){ return x >= 0.f ? x : 0.2f*x; }

// ---------------- init: amax=-inf, denom=0, agg=0 ----------------
__global__ __launch_bounds__(256) void k_init(float* __restrict__ amax,
                                              float* __restrict__ denom,
                                              float* __restrict__ agg,
                                              int n4, long nagg)
{
  long i  = (long)blockIdx.x*256 + threadIdx.x;
  long st = (long)gridDim.x*256;
  for (long j=i; j<n4;  j+=st){ amax[j] = -3.0e38f; denom[j] = 0.f; }
  for (long j=i; j<nagg; j+=st){ agg[j] = 0.f; }
}

// ---------------- GEMM [N,K] @ [K,256] + fused per-head attention dots ------
// block = 256 threads (thread t -> output col t), R=8 rows per block.
// wave w (lanes t=64w..64w+63) == head w channels -> shuffle-reduce a_src/a_dst.
template<int K>
__global__ __launch_bounds__(256) void k_gemm_att(
    const float* __restrict__ in,     // [N,K]
    const float* __restrict__ W,      // [K,256]
    const float* __restrict__ att_s,  // [4,64]
    const float* __restrict__ att_d,  // [4,64]
    float* __restrict__ h,            // [N,256]
    float* __restrict__ asrc,         // [N,4]
    float* __restrict__ adst)         // [N,4]
{
  constexpr int R = 8;
  __shared__ float xs[R][K];
  const int t = threadIdx.x;
  const long row0 = (long)blockIdx.x * R;
  for (int i = t; i < R*K; i += 256)
    xs[i / K][i % K] = in[row0*K + i];          // contiguous rows -> coalesced
  __syncthreads();

  float acc[R];
  #pragma unroll
  for (int r=0;r<R;r++) acc[r] = 0.f;
  #pragma unroll 4
  for (int k=0;k<K;k++){
    const float w = W[k*256 + t];               // coalesced, L2-resident
    #pragma unroll
    for (int r=0;r<R;r++) acc[r] += xs[r][k] * w;
  }

  const int head = t >> 6, c = t & 63;
  const float as = att_s[head*64 + c];
  const float ad = att_d[head*64 + c];
  #pragma unroll
  for (int r=0;r<R;r++){
    h[(row0+r)*256 + t] = acc[r];
    float vs = acc[r]*as, vd = acc[r]*ad;
    #pragma unroll
    for (int off=32; off; off>>=1){
      vs += __shfl_xor(vs, off, 64);
      vd += __shfl_xor(vd, off, 64);
    }
    if (c == 0){
      asrc[(row0+r)*4 + head] = vs;
      adst[(row0+r)*4 + head] = vd;
    }
  }
}

// ---------------- edge pass 1: segment max (float atomic max trick) ---------
__global__ __launch_bounds__(256) void k_edge_max(
    const int* __restrict__ ei, int E, int N,
    const float* __restrict__ asrc, const float* __restrict__ adst,
    float* __restrict__ amax)
{
  const int e = blockIdx.x*256 + threadIdx.x;
  if (e >= E + N) return;
  int s, d;
  if (e < E){ s = ei[e]; d = ei[E + e]; } else { s = d = e - E; }
  #pragma unroll
  for (int hh=0; hh<4; hh++){
    const float a = lrelu(asrc[s*4+hh] + adst[d*4+hh]);
    float* addr = &amax[d*4+hh];
    if (a >= 0.f) atomicMax((int*)addr, __float_as_int(a));
    else          atomicMin((unsigned int*)addr, (unsigned int)__float_as_int(a));
  }
}

// ---------------- edge pass 2: denom = segment_sum(exp(a - amax[dst])) ------
__global__ __launch_bounds__(256) void k_edge_denom(
    const int* __restrict__ ei, int E, int N,
    const float* __restrict__ asrc, const float* __restrict__ adst,
    const float* __restrict__ amax, float* __restrict__ denom)
{
  const int e = blockIdx.x*256 + threadIdx.x;
  if (e >= E + N) return;
  int s, d;
  if (e < E){ s = ei[e]; d = ei[E + e]; } else { s = d = e - E; }
  #pragma unroll
  for (int hh=0; hh<4; hh++){
    const float a = lrelu(asrc[s*4+hh] + adst[d*4+hh]);
    atomicAdd(&denom[d*4+hh], expf(a - amax[d*4+hh]));
  }
}

// ---------------- edge pass 3 (layer 1, concat): wave per edge, 256 ch ------
__global__ __launch_bounds__(256) void k_edge_agg1(
    const int* __restrict__ ei, int E, int N,
    const float* __restrict__ asrc, const float* __restrict__ adst,
    const float* __restrict__ amax, const float* __restrict__ denom,
    const float* __restrict__ h, float* __restrict__ agg)
{
  const long gtid = (long)blockIdx.x*256 + threadIdx.x;
  const int e = (int)(gtid >> 6);
  const int l = threadIdx.x & 63;          // channels 4l..4l+3
  if (e >= E + N) return;
  int s, d;
  if (e < E){ s = ei[e]; d = ei[E + e]; } else { s = d = e - E; }
  const int hd = l >> 4;                   // head of this lane's channels
  const float a   = lrelu(asrc[s*4+hd] + adst[d*4+hd]);
  const float wgt = expf(a - amax[d*4+hd]) / denom[d*4+hd];
  const float4 v = *(const float4*)(h + (long)s*256 + 4*l);
  float* o = agg + (long)d*256 + 4*l;
  atomicAdd(o+0, v.x*wgt);
  atomicAdd(o+1, v.y*wgt);
  atomicAdd(o+2, v.z*wgt);
  atomicAdd(o+3, v.w*wgt);
}

// ---------------- edge pass 3 (layer 2, head-mean): wave per edge, 64 ch ----
__global__ __launch_bounds__(256) void k_edge_agg2(
    const int* __restrict__ ei, int E, int N,
    const float* __restrict__ asrc, const float* __restrict__ adst,
    const float* __restrict__ amax, const float* __restrict__ denom,
    const float* __restrict__ h, float* __restrict__ agg)
{
  const long gtid = (long)blockIdx.x*256 + threadIdx.x;
  const int e = (int)(gtid >> 6);
  const int l = threadIdx.x & 63;          // output channel c
  if (e >= E + N) return;
  int s, d;
  if (e < E){ s = ei[e]; d = ei[E + e]; } else { s = d = e - E; }
  float sum = 0.f;
  #pragma unroll
  for (int hh=0; hh<4; hh++){
    const float a   = lrelu(asrc[s*4+hh] + adst[d*4+hh]);
    const float wgt = expf(a - amax[d*4+hh]) / denom[d*4+hh];
    sum += wgt * h[(long)s*256 + hh*64 + l];
  }
  atomicAdd(agg + (long)d*64 + l, 0.25f * sum);
}

// ---------------- bias + relu (in place, mod-256 bias broadcast) ------------
__global__ __launch_bounds__(256) void k_relu_bias(float* __restrict__ x,
                                                   const float* __restrict__ b,
                                                   long n)
{
  long i  = (long)blockIdx.x*256 + threadIdx.x;
  long st = (long)gridDim.x*256;
  for (; i<n; i+=st){
    const float v = x[i] + b[(int)(i & 255)];
    x[i] = v > 0.f ? v : 0.f;
  }
}

// ---------------- fused: relu(agg2+b2) -> relu(@ff1) -> @ff2 -> out ---------
__global__ __launch_bounds__(256) void k_ff(
    const float* __restrict__ agg2, const float* __restrict__ b2,
    const float* __restrict__ w1, const float* __restrict__ b1,
    const float* __restrict__ w2, const float* __restrict__ b2f,
    float* __restrict__ out, int N)
{
  __shared__ float W1s[64*32];
  __shared__ float B1s[32];
  __shared__ float W2s[64];
  __shared__ float B2s[2];
  __shared__ float Bb2[64];
  const int t = threadIdx.x;
  for (int i=t; i<64*32; i+=256) W1s[i] = w1[i];
  if (t < 32) B1s[t] = b1[t];
  if (t < 64) W2s[t] = w2[t];
  if (t < 2)  B2s[t] = b2f[t];
  if (t < 64) Bb2[t] = b2[t];
  __syncthreads();

  const int n = blockIdx.x*256 + t;
  if (n >= N) return;

  float f[64];
  #pragma unroll
  for (int c=0;c<64;c++){
    const float v = agg2[(long)n*64 + c] + Bb2[c];
    f[c] = v > 0.f ? v : 0.f;
  }
  float t1[32];
  #pragma unroll
  for (int j=0;j<32;j++) t1[j] = B1s[j];
  #pragma unroll
  for (int c=0;c<64;c++){
    const float fc = f[c];
    #pragma unroll
    for (int j=0;j<32;j++) t1[j] += fc * W1s[c*32 + j];
  }
  float o0 = B2s[0], o1 = B2s[1];
  #pragma unroll
  for (int j=0;j<32;j++){
    const float v = t1[j] > 0.f ? t1[j] : 0.f;
    o0 += v * W2s[j*2 + 0];
    o1 += v * W2s[j*2 + 1];
  }
  out[(long)n*2 + 0] = o0;
  out[(long)n*2 + 1] = o1;
}

extern "C" void kernel_launch(void* const* d_in, const int* in_sizes, int n_in,
                              void* d_out, int out_size, void* d_ws, size_t ws_size,
                              hipStream_t stream)
{
  const float* x      = (const float*)d_in[0];
  const int*   ei     = (const int*)  d_in[1];   // [2,E] (self loops appended on the fly)
  const float* W1     = (const float*)d_in[3];
  const float* att_s1 = (const float*)d_in[4];
  const float* att_d1 = (const float*)d_in[5];
  const float* b1     = (const float*)d_in[6];
  const float* W2     = (const float*)d_in[7];
  const float* att_s2 = (const float*)d_in[8];
  const float* att_d2 = (const float*)d_in[9];
  const float* b2     = (const float*)d_in[10];
  const float* ff1w   = (const float*)d_in[11];
  const float* ff1b   = (const float*)d_in[12];
  const float* ff2w   = (const float*)d_in[13];
  const float* ff2b   = (const float*)d_in[14];
  float* out = (float*)d_out;

  const int N = in_sizes[0] / 128;
  const int E = in_sizes[1] / 2;
  const int tot = E + N;

  float* ws   = (float*)d_ws;
  float* h    = ws;                         // [N,256]  (h1, then reused as h2)
  float* agg1 = h    + (size_t)N*256;       // [N,256]  (layer-1 out -> layer-2 in)
  float* asrc = agg1 + (size_t)N*256;       // [N,4]
  float* adst = asrc + (size_t)N*4;         // [N,4]
  float* amax = adst + (size_t)N*4;         // [N,4]
  float* denom= amax + (size_t)N*4;         // [N,4]
  float* agg2 = denom+ (size_t)N*4;         // [N,64]

  const int gE = (tot + 255) / 256;                 // thread per edge
  const int gW = (int)(((long)tot*64 + 255) / 256); // wave per edge

  // ---- layer 1 (concat heads) ----
  k_init<<<2048,256,0,stream>>>(amax, denom, agg1, N*4, (long)N*256);
  k_gemm_att<128><<<N/8,256,0,stream>>>(x, W1, att_s1, att_d1, h, asrc, adst);
  k_edge_max  <<<gE,256,0,stream>>>(ei, E, N, asrc, adst, amax);
  k_edge_denom<<<gE,256,0,stream>>>(ei, E, N, asrc, adst, amax, denom);
  k_edge_agg1 <<<gW,256,0,stream>>>(ei, E, N, asrc, adst, amax, denom, h, agg1);
  k_relu_bias <<<2048,256,0,stream>>>(agg1, b1, (long)N*256);

  // ---- layer 2 (head mean) ----
  k_init<<<2048,256,0,stream>>>(amax, denom, agg2, N*4, (long)N*64);
  k_gemm_att<256><<<N/8,256,0,stream>>>(agg1, W2, att_s2, att_d2, h, asrc, adst);
  k_edge_max  <<<gE,256,0,stream>>>(ei, E, N, asrc, adst, amax);
  k_edge_denom<<<gE,256,0,stream>>>(ei, E, N, asrc, adst, amax, denom);
  k_edge_agg2 <<<gW,256,0,stream>>>(ei, E, N, asrc, adst, amax, denom, h, agg2);

  // ---- feed-forward head ----
  k_ff<<<(N+255)/256,256,0,stream>>>(agg2, b2, ff1w, ff1b, ff2w, ff2b, out, N);
}

// Round 2
// 724.774 us; speedup vs baseline: 5.4413x; 5.4413x over previous
//
#include <hip/hip_runtime.h>

__device__ __forceinline__ float lrelu(float x){ return x >= 0.f ? x : 0.2f*x; }

// ---------------- zero degree counters ----------------
__global__ __launch_bounds__(256) void k_zero(int* __restrict__ p, int n)
{
  int i = blockIdx.x*256 + threadIdx.x;
  if (i < n) p[i] = 0;
}

// ---------------- count in-degree per destination ----------------
__global__ __launch_bounds__(256) void k_count(const int* __restrict__ ei,
                                               int E, int N, int* __restrict__ deg)
{
  const int e = blockIdx.x*256 + threadIdx.x;
  if (e >= E + N) return;
  const int d = (e < E) ? ei[E + e] : (e - E);
  atomicAdd(&deg[d], 1);
}

// ---------------- exclusive prefix scan (single block) ----------------
__global__ __launch_bounds__(256) void k_scan(const int* __restrict__ deg,
                                              int* __restrict__ rowptr,
                                              int* __restrict__ cursor, int N)
{
  __shared__ int sums[256];
  const int t = threadIdx.x;
  const int chunk = (N + 255) / 256;
  const int lo = t * chunk;
  const int hi = min(lo + chunk, N);
  int s = 0;
  for (int i = lo; i < hi; i++) s += deg[i];
  sums[t] = s;
  __syncthreads();
  if (t == 0){
    int acc = 0;
    for (int i = 0; i < 256; i++){ int v = sums[i]; sums[i] = acc; acc += v; }
  }
  __syncthreads();
  int acc = sums[t];
  for (int i = lo; i < hi; i++){
    rowptr[i] = acc; cursor[i] = acc; acc += deg[i];
  }
  if (hi == N) rowptr[N] = acc;
}

// ---------------- fill CSR src lists ----------------
__global__ __launch_bounds__(256) void k_fill(const int* __restrict__ ei,
                                              int E, int N, int* __restrict__ cursor,
                                              int* __restrict__ csr)
{
  const int e = blockIdx.x*256 + threadIdx.x;
  if (e >= E + N) return;
  int s, d;
  if (e < E){ s = ei[e]; d = ei[E + e]; } else { s = d = e - E; }
  const int pos = atomicAdd(&cursor[d], 1);
  csr[pos] = s;
}

// ---------------- GEMM [N,K] @ [K,256] + fused per-head attention dots ------
// thread t -> output col t; R rows per block; wave w == head w -> shuffle dot.
template<int K, int R>
__global__ __launch_bounds__(256) void k_gemm_att(
    const float* __restrict__ in,     // [N,K]
    const float* __restrict__ W,      // [K,256]
    const float* __restrict__ att_s,  // [4,64]
    const float* __restrict__ att_d,  // [4,64]
    float* __restrict__ h,            // [N,256]
    float* __restrict__ asrc,         // [N,4]
    float* __restrict__ adst)         // [N,4]
{
  __shared__ float xs[R][K];
  const int t = threadIdx.x;
  const long row0 = (long)blockIdx.x * R;
  for (int i = t; i < R*K; i += 256)
    xs[i / K][i % K] = in[row0*K + i];          // contiguous rows -> coalesced
  __syncthreads();

  float acc[R];
  #pragma unroll
  for (int r=0;r<R;r++) acc[r] = 0.f;
  #pragma unroll 4
  for (int k=0;k<K;k++){
    const float w = W[k*256 + t];               // 1 L2 load per R FMA
    #pragma unroll
    for (int r=0;r<R;r++) acc[r] += xs[r][k] * w;   // LDS broadcast reads
  }

  const int head = t >> 6, c = t & 63;
  const float as = att_s[head*64 + c];
  const float ad = att_d[head*64 + c];
  #pragma unroll
  for (int r=0;r<R;r++){
    h[(row0+r)*256 + t] = acc[r];
    float vs = acc[r]*as, vd = acc[r]*ad;
    #pragma unroll
    for (int off=32; off; off>>=1){
      vs += __shfl_xor(vs, off, 64);
      vd += __shfl_xor(vd, off, 64);
    }
    if (c == 0){
      asrc[(row0+r)*4 + head] = vs;
      adst[(row0+r)*4 + head] = vd;
    }
  }
}

// ---------------- layer-1 aggregation: wave per dst node, gather-based ------
// softmax (max->denom->weight) + weighted gather + bias + relu, fused.
__global__ __launch_bounds__(256) void k_node_agg1(
    const int* __restrict__ rowptr, const int* __restrict__ csr,
    const float* __restrict__ asrc, const float* __restrict__ adst,
    const float* __restrict__ h, const float* __restrict__ bias,
    float* __restrict__ outp, int N)
{
  const int n = blockIdx.x*4 + (threadIdx.x >> 6);
  const int l = threadIdx.x & 63;
  if (n >= N) return;
  const int start = rowptr[n];
  const int deg = rowptr[n+1] - start;
  const float4 ad = *(const float4*)(adst + (size_t)n*4);

  // phase 1: per-head max over incoming edges
  float4 m = make_float4(-3.0e38f,-3.0e38f,-3.0e38f,-3.0e38f);
  for (int i = l; i < deg; i += 64){
    const int s = csr[start + i];
    const float4 as = *(const float4*)(asrc + (size_t)s*4);
    m.x = fmaxf(m.x, lrelu(as.x + ad.x));
    m.y = fmaxf(m.y, lrelu(as.y + ad.y));
    m.z = fmaxf(m.z, lrelu(as.z + ad.z));
    m.w = fmaxf(m.w, lrelu(as.w + ad.w));
  }
  #pragma unroll
  for (int off=32; off; off>>=1){
    m.x = fmaxf(m.x, __shfl_xor(m.x, off, 64));
    m.y = fmaxf(m.y, __shfl_xor(m.y, off, 64));
    m.z = fmaxf(m.z, __shfl_xor(m.z, off, 64));
    m.w = fmaxf(m.w, __shfl_xor(m.w, off, 64));
  }
  // phase 2: per-head denom
  float4 ds = make_float4(0.f,0.f,0.f,0.f);
  for (int i = l; i < deg; i += 64){
    const int s = csr[start + i];
    const float4 as = *(const float4*)(asrc + (size_t)s*4);
    ds.x += expf(lrelu(as.x + ad.x) - m.x);
    ds.y += expf(lrelu(as.y + ad.y) - m.y);
    ds.z += expf(lrelu(as.z + ad.z) - m.z);
    ds.w += expf(lrelu(as.w + ad.w) - m.w);
  }
  #pragma unroll
  for (int off=32; off; off>>=1){
    ds.x += __shfl_xor(ds.x, off, 64);
    ds.y += __shfl_xor(ds.y, off, 64);
    ds.z += __shfl_xor(ds.z, off, 64);
    ds.w += __shfl_xor(ds.w, off, 64);
  }
  // lane's head-specific constants (no dynamic register indexing)
  const int hd = l >> 4;
  const float adh = hd==0?ad.x : hd==1?ad.y : hd==2?ad.z : ad.w;
  const float mh  = hd==0?m.x  : hd==1?m.y  : hd==2?m.z  : m.w;
  const float dih = 1.f / (hd==0?ds.x : hd==1?ds.y : hd==2?ds.z : ds.w);

  // phase 3: weighted gather, channels 4l..4l+3
  float4 acc = make_float4(0.f,0.f,0.f,0.f);
  int s_next = csr[start];
  for (int e = 0; e < deg; e++){
    const int s = s_next;
    if (e+1 < deg) s_next = csr[start + e + 1];
    const float wgt = expf(lrelu(asrc[(size_t)s*4 + hd] + adh) - mh) * dih;
    const float4 v = *(const float4*)(h + (size_t)s*256 + 4*l);
    acc.x += v.x*wgt; acc.y += v.y*wgt; acc.z += v.z*wgt; acc.w += v.w*wgt;
  }
  const float4 b = *(const float4*)(bias + 4*l);
  float4 o;
  o.x = fmaxf(acc.x + b.x, 0.f);
  o.y = fmaxf(acc.y + b.y, 0.f);
  o.z = fmaxf(acc.z + b.z, 0.f);
  o.w = fmaxf(acc.w + b.w, 0.f);
  *(float4*)(outp + (size_t)n*256 + 4*l) = o;
}

// ---------------- layer-2 aggregation: wave per dst node, head-mean ---------
__global__ __launch_bounds__(256) void k_node_agg2(
    const int* __restrict__ rowptr, const int* __restrict__ csr,
    const float* __restrict__ asrc, const float* __restrict__ adst,
    const float* __restrict__ h, const float* __restrict__ bias,
    float* __restrict__ outp, int N)
{
  const int n = blockIdx.x*4 + (threadIdx.x >> 6);
  const int l = threadIdx.x & 63;          // output channel
  if (n >= N) return;
  const int start = rowptr[n];
  const int deg = rowptr[n+1] - start;
  const float4 ad = *(const float4*)(adst + (size_t)n*4);

  float4 m = make_float4(-3.0e38f,-3.0e38f,-3.0e38f,-3.0e38f);
  for (int i = l; i < deg; i += 64){
    const int s = csr[start + i];
    const float4 as = *(const float4*)(asrc + (size_t)s*4);
    m.x = fmaxf(m.x, lrelu(as.x + ad.x));
    m.y = fmaxf(m.y, lrelu(as.y + ad.y));
    m.z = fmaxf(m.z, lrelu(as.z + ad.z));
    m.w = fmaxf(m.w, lrelu(as.w + ad.w));
  }
  #pragma unroll
  for (int off=32; off; off>>=1){
    m.x = fmaxf(m.x, __shfl_xor(m.x, off, 64));
    m.y = fmaxf(m.y, __shfl_xor(m.y, off, 64));
    m.z = fmaxf(m.z, __shfl_xor(m.z, off, 64));
    m.w = fmaxf(m.w, __shfl_xor(m.w, off, 64));
  }
  float4 ds = make_float4(0.f,0.f,0.f,0.f);
  for (int i = l; i < deg; i += 64){
    const int s = csr[start + i];
    const float4 as = *(const float4*)(asrc + (size_t)s*4);
    ds.x += expf(lrelu(as.x + ad.x) - m.x);
    ds.y += expf(lrelu(as.y + ad.y) - m.y);
    ds.z += expf(lrelu(as.z + ad.z) - m.z);
    ds.w += expf(lrelu(as.w + ad.w) - m.w);
  }
  #pragma unroll
  for (int off=32; off; off>>=1){
    ds.x += __shfl_xor(ds.x, off, 64);
    ds.y += __shfl_xor(ds.y, off, 64);
    ds.z += __shfl_xor(ds.z, off, 64);
    ds.w += __shfl_xor(ds.w, off, 64);
  }
  const float4 di = make_float4(1.f/ds.x, 1.f/ds.y, 1.f/ds.z, 1.f/ds.w);

  float acc = 0.f;
  int s_next = csr[start];
  for (int e = 0; e < deg; e++){
    const int s = s_next;
    if (e+1 < deg) s_next = csr[start + e + 1];
    const float4 as = *(const float4*)(asrc + (size_t)s*4);
    const float w0 = expf(lrelu(as.x + ad.x) - m.x) * di.x;
    const float w1 = expf(lrelu(as.y + ad.y) - m.y) * di.y;
    const float w2 = expf(lrelu(as.z + ad.z) - m.z) * di.z;
    const float w3 = expf(lrelu(as.w + ad.w) - m.w) * di.w;
    const float* hs = h + (size_t)s*256;
    acc += w0*hs[l] + w1*hs[64+l] + w2*hs[128+l] + w3*hs[192+l];
  }
  acc = 0.25f * acc + bias[l];
  outp[(size_t)n*64 + l] = fmaxf(acc, 0.f);   // relu fused
}

// ---------------- FF head: (pre-activated) agg2 -> relu(@ff1) -> @ff2 -------
__global__ __launch_bounds__(256) void k_ff(
    const float* __restrict__ agg2,
    const float* __restrict__ w1, const float* __restrict__ b1,
    const float* __restrict__ w2, const float* __restrict__ b2f,
    float* __restrict__ out, int N)
{
  __shared__ float W1s[64*32];
  __shared__ float B1s[32];
  __shared__ float W2s[64];
  __shared__ float B2s[2];
  const int t = threadIdx.x;
  for (int i=t; i<64*32; i+=256) W1s[i] = w1[i];
  if (t < 32) B1s[t] = b1[t];
  if (t < 64) W2s[t] = w2[t];
  if (t < 2)  B2s[t] = b2f[t];
  __syncthreads();

  const int n = blockIdx.x*256 + t;
  if (n >= N) return;

  float t1[32];
  #pragma unroll
  for (int j=0;j<32;j++) t1[j] = B1s[j];
  #pragma unroll
  for (int c=0;c<64;c++){
    const float fc = agg2[(long)n*64 + c];
    #pragma unroll
    for (int j=0;j<32;j++) t1[j] += fc * W1s[c*32 + j];
  }
  float o0 = B2s[0], o1 = B2s[1];
  #pragma unroll
  for (int j=0;j<32;j++){
    const float v = t1[j] > 0.f ? t1[j] : 0.f;
    o0 += v * W2s[j*2 + 0];
    o1 += v * W2s[j*2 + 1];
  }
  out[(long)n*2 + 0] = o0;
  out[(long)n*2 + 1] = o1;
}

extern "C" void kernel_launch(void* const* d_in, const int* in_sizes, int n_in,
                              void* d_out, int out_size, void* d_ws, size_t ws_size,
                              hipStream_t stream)
{
  const float* x      = (const float*)d_in[0];
  const int*   ei     = (const int*)  d_in[1];
  const float* W1     = (const float*)d_in[3];
  const float* att_s1 = (const float*)d_in[4];
  const float* att_d1 = (const float*)d_in[5];
  const float* b1     = (const float*)d_in[6];
  const float* W2     = (const float*)d_in[7];
  const float* att_s2 = (const float*)d_in[8];
  const float* att_d2 = (const float*)d_in[9];
  const float* b2     = (const float*)d_in[10];
  const float* ff1w   = (const float*)d_in[11];
  const float* ff1b   = (const float*)d_in[12];
  const float* ff2w   = (const float*)d_in[13];
  const float* ff2b   = (const float*)d_in[14];
  float* out = (float*)d_out;

  const int N = in_sizes[0] / 128;
  const int E = in_sizes[1] / 2;
  const int tot = E + N;

  // ---- workspace layout ----
  char* p = (char*)d_ws;
  float* h    = (float*)p;  p += (size_t)N*256*4;   // [N,256]
  float* agg1 = (float*)p;  p += (size_t)N*256*4;   // [N,256]
  float* agg2 = (float*)p;  p += (size_t)N*64*4;    // [N,64]
  float* asrc = (float*)p;  p += (size_t)N*4*4;     // [N,4]
  float* adst = (float*)p;  p += (size_t)N*4*4;     // [N,4]
  int* deg    = (int*)p;    p += (size_t)N*4;
  int* rowptr = (int*)p;    p += (size_t)(N+1)*4;
  int* cursor = (int*)p;    p += (size_t)N*4;
  int* csr    = (int*)p;    p += (size_t)tot*4;

  const int gE = (tot + 255) / 256;
  const int gN4 = (N + 3) / 4;

  // ---- CSR build (shared by both layers) ----
  k_zero <<<(N+255)/256,256,0,stream>>>(deg, N);
  k_count<<<gE,256,0,stream>>>(ei, E, N, deg);
  k_scan <<<1,256,0,stream>>>(deg, rowptr, cursor, N);
  k_fill <<<gE,256,0,stream>>>(ei, E, N, cursor, csr);

  // ---- layer 1 (concat heads) ----
  k_gemm_att<128,16><<<(N+15)/16,256,0,stream>>>(x, W1, att_s1, att_d1, h, asrc, adst);
  k_node_agg1<<<gN4,256,0,stream>>>(rowptr, csr, asrc, adst, h, b1, agg1, N);

  // ---- layer 2 (head mean) ----
  k_gemm_att<256,16><<<(N+15)/16,256,0,stream>>>(agg1, W2, att_s2, att_d2, h, asrc, adst);
  k_node_agg2<<<gN4,256,0,stream>>>(rowptr, csr, asrc, adst, h, b2, agg2, N);

  // ---- feed-forward head ----
  k_ff<<<(N+255)/256,256,0,stream>>>(agg2, ff1w, ff1b, ff2w, ff2b, out, N);
}

// Round 3
// 652.509 us; speedup vs baseline: 6.0439x; 1.1107x over previous
//
#include <hip/hip_runtime.h>

__device__ __forceinline__ float lrelu(float x){ return x >= 0.f ? x : 0.2f*x; }

// ---------------- zero degree counters ----------------
__global__ __launch_bounds__(256) void k_zero(int* __restrict__ p, int n)
{
  int i = blockIdx.x*256 + threadIdx.x;
  if (i < n) p[i] = 0;
}

// ---------------- count in-degree per destination ----------------
__global__ __launch_bounds__(256) void k_count(const int* __restrict__ ei,
                                               int E, int N, int* __restrict__ deg)
{
  const int e = blockIdx.x*256 + threadIdx.x;
  if (e >= E + N) return;
  const int d = (e < E) ? ei[E + e] : (e - E);
  atomicAdd(&deg[d], 1);
}

// ---------------- exclusive prefix scan (single block) ----------------
__global__ __launch_bounds__(256) void k_scan(const int* __restrict__ deg,
                                              int* __restrict__ rowptr,
                                              int* __restrict__ cursor, int N)
{
  __shared__ int sums[256];
  const int t = threadIdx.x;
  const int chunk = (N + 255) / 256;
  const int lo = t * chunk;
  const int hi = min(lo + chunk, N);
  int s = 0;
  for (int i = lo; i < hi; i++) s += deg[i];
  sums[t] = s;
  __syncthreads();
  if (t == 0){
    int acc = 0;
    for (int i = 0; i < 256; i++){ int v = sums[i]; sums[i] = acc; acc += v; }
  }
  __syncthreads();
  int acc = sums[t];
  for (int i = lo; i < hi; i++){
    rowptr[i] = acc; cursor[i] = acc; acc += deg[i];
  }
  if (hi == N) rowptr[N] = acc;
}

// ---------------- fill CSR src lists ----------------
__global__ __launch_bounds__(256) void k_fill(const int* __restrict__ ei,
                                              int E, int N, int* __restrict__ cursor,
                                              int* __restrict__ csr)
{
  const int e = blockIdx.x*256 + threadIdx.x;
  if (e >= E + N) return;
  int s, d;
  if (e < E){ s = ei[e]; d = ei[E + e]; } else { s = d = e - E; }
  const int pos = atomicAdd(&cursor[d], 1);
  csr[pos] = s;
}

// ---------------- register-tiled GEMM [N,K]@[K,256] + fused attention dots --
// block: 64 rows x 128 cols (= heads cb*2, cb*2+1). thread: 4 rows x 8 cols.
// A staged transposed (Ast[k][row]) so per-k A-frag is one float4.
template<int K>
__global__ __launch_bounds__(256) void k_gemm_att(
    const float* __restrict__ in,     // [N,K]
    const float* __restrict__ W,      // [K,256]
    const float* __restrict__ att_s,  // [4,64]
    const float* __restrict__ att_d,  // [4,64]
    float* __restrict__ h,            // [N,256]
    float* __restrict__ asrc,         // [N,4]
    float* __restrict__ adst,         // [N,4]
    int N)
{
  constexpr int KC = 32;
  __shared__ float Ast[KC][68];    // [k][row], padded: 16B-aligned rows, no conflict
  __shared__ float Bs[KC][132];    // [k][col], padded
  const int t  = threadIdx.x;
  const int tx = t & 15, ty = t >> 4;
  const int m0 = (blockIdx.x >> 1) * 64;
  const int cb = blockIdx.x & 1;           // col block: heads {2cb, 2cb+1}

  float acc[4][8];
  #pragma unroll
  for (int i=0;i<4;i++)
    #pragma unroll
    for (int j=0;j<8;j++) acc[i][j] = 0.f;

  for (int k0 = 0; k0 < K; k0 += KC){
    __syncthreads();
    // stage A: 64 rows x 32 k  (2 float4/thread), transpose into Ast
    #pragma unroll
    for (int i = 0; i < 2; i++){
      const int idx = t + i*256;
      const int r = idx >> 3;
      const int c4 = (idx & 7) * 4;
      const int rg = min(m0 + r, N-1);          // clamp tail block
      const float4 v = *(const float4*)(in + (size_t)rg*K + k0 + c4);
      Ast[c4+0][r] = v.x; Ast[c4+1][r] = v.y;
      Ast[c4+2][r] = v.z; Ast[c4+3][r] = v.w;
    }
    // stage B: 32 k x 128 cols (4 float4/thread)
    #pragma unroll
    for (int i = 0; i < 4; i++){
      const int idx = t + i*256;
      const int kr = idx >> 5;
      const int cc = (idx & 31) * 4;
      *(float4*)(&Bs[kr][cc]) = *(const float4*)(W + (size_t)(k0+kr)*256 + cb*128 + cc);
    }
    __syncthreads();
    #pragma unroll 8
    for (int kk = 0; kk < KC; kk++){
      const float4 a  = *(const float4*)(&Ast[kk][ty*4]);
      const float4 b0 = *(const float4*)(&Bs[kk][tx*4]);        // head 2cb
      const float4 b1 = *(const float4*)(&Bs[kk][64 + tx*4]);   // head 2cb+1
      const float av[4] = {a.x, a.y, a.z, a.w};
      const float bv[8] = {b0.x,b0.y,b0.z,b0.w, b1.x,b1.y,b1.z,b1.w};
      #pragma unroll
      for (int i=0;i<4;i++)
        #pragma unroll
        for (int j=0;j<8;j++) acc[i][j] += av[i] * bv[j];
    }
  }

  // epilogue: store h + fused per-head attention dots
  const int h0 = cb*2, h1 = cb*2 + 1;
  float as0[4], ad0[4], as1[4], ad1[4];
  #pragma unroll
  for (int j=0;j<4;j++){
    as0[j] = att_s[h0*64 + tx*4 + j];
    ad0[j] = att_d[h0*64 + tx*4 + j];
    as1[j] = att_s[h1*64 + tx*4 + j];
    ad1[j] = att_d[h1*64 + tx*4 + j];
  }
  #pragma unroll
  for (int i=0;i<4;i++){
    const int row = m0 + ty*4 + i;
    const bool ok = row < N;
    if (ok){
      float4 o0 = make_float4(acc[i][0],acc[i][1],acc[i][2],acc[i][3]);
      float4 o1 = make_float4(acc[i][4],acc[i][5],acc[i][6],acc[i][7]);
      *(float4*)(h + (size_t)row*256 + cb*128 + tx*4)      = o0;
      *(float4*)(h + (size_t)row*256 + cb*128 + 64 + tx*4) = o1;
    }
    float vs0 = acc[i][0]*as0[0] + acc[i][1]*as0[1] + acc[i][2]*as0[2] + acc[i][3]*as0[3];
    float vd0 = acc[i][0]*ad0[0] + acc[i][1]*ad0[1] + acc[i][2]*ad0[2] + acc[i][3]*ad0[3];
    float vs1 = acc[i][4]*as1[0] + acc[i][5]*as1[1] + acc[i][6]*as1[2] + acc[i][7]*as1[3];
    float vd1 = acc[i][4]*ad1[0] + acc[i][5]*ad1[1] + acc[i][6]*ad1[2] + acc[i][7]*ad1[3];
    #pragma unroll
    for (int off=1; off<16; off<<=1){
      vs0 += __shfl_xor(vs0, off, 16);
      vd0 += __shfl_xor(vd0, off, 16);
      vs1 += __shfl_xor(vs1, off, 16);
      vd1 += __shfl_xor(vd1, off, 16);
    }
    if (tx == 0 && ok){
      asrc[(size_t)row*4 + h0] = vs0;
      adst[(size_t)row*4 + h0] = vd0;
      asrc[(size_t)row*4 + h1] = vs1;
      adst[(size_t)row*4 + h1] = vd1;
    }
  }
}

// ---------------- layer-1 aggregation: wave per dst node, gather-based ------
__global__ __launch_bounds__(256) void k_node_agg1(
    const int* __restrict__ rowptr, const int* __restrict__ csr,
    const float* __restrict__ asrc, const float* __restrict__ adst,
    const float* __restrict__ h, const float* __restrict__ bias,
    float* __restrict__ outp, int N)
{
  const int n = blockIdx.x*4 + (threadIdx.x >> 6);
  const int l = threadIdx.x & 63;
  if (n >= N) return;
  const int start = rowptr[n];
  const int deg = rowptr[n+1] - start;
  const float4 ad = *(const float4*)(adst + (size_t)n*4);

  float4 m = make_float4(-3.0e38f,-3.0e38f,-3.0e38f,-3.0e38f);
  for (int i = l; i < deg; i += 64){
    const int s = csr[start + i];
    const float4 as = *(const float4*)(asrc + (size_t)s*4);
    m.x = fmaxf(m.x, lrelu(as.x + ad.x));
    m.y = fmaxf(m.y, lrelu(as.y + ad.y));
    m.z = fmaxf(m.z, lrelu(as.z + ad.z));
    m.w = fmaxf(m.w, lrelu(as.w + ad.w));
  }
  #pragma unroll
  for (int off=32; off; off>>=1){
    m.x = fmaxf(m.x, __shfl_xor(m.x, off, 64));
    m.y = fmaxf(m.y, __shfl_xor(m.y, off, 64));
    m.z = fmaxf(m.z, __shfl_xor(m.z, off, 64));
    m.w = fmaxf(m.w, __shfl_xor(m.w, off, 64));
  }
  float4 ds = make_float4(0.f,0.f,0.f,0.f);
  for (int i = l; i < deg; i += 64){
    const int s = csr[start + i];
    const float4 as = *(const float4*)(asrc + (size_t)s*4);
    ds.x += expf(lrelu(as.x + ad.x) - m.x);
    ds.y += expf(lrelu(as.y + ad.y) - m.y);
    ds.z += expf(lrelu(as.z + ad.z) - m.z);
    ds.w += expf(lrelu(as.w + ad.w) - m.w);
  }
  #pragma unroll
  for (int off=32; off; off>>=1){
    ds.x += __shfl_xor(ds.x, off, 64);
    ds.y += __shfl_xor(ds.y, off, 64);
    ds.z += __shfl_xor(ds.z, off, 64);
    ds.w += __shfl_xor(ds.w, off, 64);
  }
  const int hd = l >> 4;
  const float adh = hd==0?ad.x : hd==1?ad.y : hd==2?ad.z : ad.w;
  const float mh  = hd==0?m.x  : hd==1?m.y  : hd==2?m.z  : m.w;
  const float dih = 1.f / (hd==0?ds.x : hd==1?ds.y : hd==2?ds.z : ds.w);

  float4 acc = make_float4(0.f,0.f,0.f,0.f);
  int s_next = csr[start];
  for (int e = 0; e < deg; e++){
    const int s = s_next;
    if (e+1 < deg) s_next = csr[start + e + 1];
    const float wgt = expf(lrelu(asrc[(size_t)s*4 + hd] + adh) - mh) * dih;
    const float4 v = *(const float4*)(h + (size_t)s*256 + 4*l);
    acc.x += v.x*wgt; acc.y += v.y*wgt; acc.z += v.z*wgt; acc.w += v.w*wgt;
  }
  const float4 b = *(const float4*)(bias + 4*l);
  float4 o;
  o.x = fmaxf(acc.x + b.x, 0.f);
  o.y = fmaxf(acc.y + b.y, 0.f);
  o.z = fmaxf(acc.z + b.z, 0.f);
  o.w = fmaxf(acc.w + b.w, 0.f);
  *(float4*)(outp + (size_t)n*256 + 4*l) = o;
}

// ---------------- layer-2 aggregation: wave per dst node, head-mean ---------
__global__ __launch_bounds__(256) void k_node_agg2(
    const int* __restrict__ rowptr, const int* __restrict__ csr,
    const float* __restrict__ asrc, const float* __restrict__ adst,
    const float* __restrict__ h, const float* __restrict__ bias,
    float* __restrict__ outp, int N)
{
  const int n = blockIdx.x*4 + (threadIdx.x >> 6);
  const int l = threadIdx.x & 63;
  if (n >= N) return;
  const int start = rowptr[n];
  const int deg = rowptr[n+1] - start;
  const float4 ad = *(const float4*)(adst + (size_t)n*4);

  float4 m = make_float4(-3.0e38f,-3.0e38f,-3.0e38f,-3.0e38f);
  for (int i = l; i < deg; i += 64){
    const int s = csr[start + i];
    const float4 as = *(const float4*)(asrc + (size_t)s*4);
    m.x = fmaxf(m.x, lrelu(as.x + ad.x));
    m.y = fmaxf(m.y, lrelu(as.y + ad.y));
    m.z = fmaxf(m.z, lrelu(as.z + ad.z));
    m.w = fmaxf(m.w, lrelu(as.w + ad.w));
  }
  #pragma unroll
  for (int off=32; off; off>>=1){
    m.x = fmaxf(m.x, __shfl_xor(m.x, off, 64));
    m.y = fmaxf(m.y, __shfl_xor(m.y, off, 64));
    m.z = fmaxf(m.z, __shfl_xor(m.z, off, 64));
    m.w = fmaxf(m.w, __shfl_xor(m.w, off, 64));
  }
  float4 ds = make_float4(0.f,0.f,0.f,0.f);
  for (int i = l; i < deg; i += 64){
    const int s = csr[start + i];
    const float4 as = *(const float4*)(asrc + (size_t)s*4);
    ds.x += expf(lrelu(as.x + ad.x) - m.x);
    ds.y += expf(lrelu(as.y + ad.y) - m.y);
    ds.z += expf(lrelu(as.z + ad.z) - m.z);
    ds.w += expf(lrelu(as.w + ad.w) - m.w);
  }
  #pragma unroll
  for (int off=32; off; off>>=1){
    ds.x += __shfl_xor(ds.x, off, 64);
    ds.y += __shfl_xor(ds.y, off, 64);
    ds.z += __shfl_xor(ds.z, off, 64);
    ds.w += __shfl_xor(ds.w, off, 64);
  }
  const float4 di = make_float4(1.f/ds.x, 1.f/ds.y, 1.f/ds.z, 1.f/ds.w);

  float acc = 0.f;
  int s_next = csr[start];
  for (int e = 0; e < deg; e++){
    const int s = s_next;
    if (e+1 < deg) s_next = csr[start + e + 1];
    const float4 as = *(const float4*)(asrc + (size_t)s*4);
    const float w0 = expf(lrelu(as.x + ad.x) - m.x) * di.x;
    const float w1 = expf(lrelu(as.y + ad.y) - m.y) * di.y;
    const float w2 = expf(lrelu(as.z + ad.z) - m.z) * di.z;
    const float w3 = expf(lrelu(as.w + ad.w) - m.w) * di.w;
    const float* hs = h + (size_t)s*256;
    acc += w0*hs[l] + w1*hs[64+l] + w2*hs[128+l] + w3*hs[192+l];
  }
  acc = 0.25f * acc + bias[l];
  outp[(size_t)n*64 + l] = fmaxf(acc, 0.f);
}

// ---------------- FF head: agg2 -> relu(@ff1) -> @ff2 -------
__global__ __launch_bounds__(256) void k_ff(
    const float* __restrict__ agg2,
    const float* __restrict__ w1, const float* __restrict__ b1,
    const float* __restrict__ w2, const float* __restrict__ b2f,
    float* __restrict__ out, int N)
{
  __shared__ float W1s[64*32];
  __shared__ float B1s[32];
  __shared__ float W2s[64];
  __shared__ float B2s[2];
  const int t = threadIdx.x;
  for (int i=t; i<64*32; i+=256) W1s[i] = w1[i];
  if (t < 32) B1s[t] = b1[t];
  if (t < 64) W2s[t] = w2[t];
  if (t < 2)  B2s[t] = b2f[t];
  __syncthreads();

  const int n = blockIdx.x*256 + t;
  if (n >= N) return;

  float t1[32];
  #pragma unroll
  for (int j=0;j<32;j++) t1[j] = B1s[j];
  #pragma unroll
  for (int c=0;c<64;c++){
    const float fc = agg2[(long)n*64 + c];
    #pragma unroll
    for (int j=0;j<32;j++) t1[j] += fc * W1s[c*32 + j];
  }
  float o0 = B2s[0], o1 = B2s[1];
  #pragma unroll
  for (int j=0;j<32;j++){
    const float v = t1[j] > 0.f ? t1[j] : 0.f;
    o0 += v * W2s[j*2 + 0];
    o1 += v * W2s[j*2 + 1];
  }
  out[(long)n*2 + 0] = o0;
  out[(long)n*2 + 1] = o1;
}

extern "C" void kernel_launch(void* const* d_in, const int* in_sizes, int n_in,
                              void* d_out, int out_size, void* d_ws, size_t ws_size,
                              hipStream_t stream)
{
  const float* x      = (const float*)d_in[0];
  const int*   ei     = (const int*)  d_in[1];
  const float* W1     = (const float*)d_in[3];
  const float* att_s1 = (const float*)d_in[4];
  const float* att_d1 = (const float*)d_in[5];
  const float* b1     = (const float*)d_in[6];
  const float* W2     = (const float*)d_in[7];
  const float* att_s2 = (const float*)d_in[8];
  const float* att_d2 = (const float*)d_in[9];
  const float* b2     = (const float*)d_in[10];
  const float* ff1w   = (const float*)d_in[11];
  const float* ff1b   = (const float*)d_in[12];
  const float* ff2w   = (const float*)d_in[13];
  const float* ff2b   = (const float*)d_in[14];
  float* out = (float*)d_out;

  const int N = in_sizes[0] / 128;
  const int E = in_sizes[1] / 2;
  const int tot = E + N;

  char* p = (char*)d_ws;
  float* h    = (float*)p;  p += (size_t)N*256*4;
  float* agg1 = (float*)p;  p += (size_t)N*256*4;
  float* agg2 = (float*)p;  p += (size_t)N*64*4;
  float* asrc = (float*)p;  p += (size_t)N*4*4;
  float* adst = (float*)p;  p += (size_t)N*4*4;
  int* deg    = (int*)p;    p += (size_t)N*4;
  int* rowptr = (int*)p;    p += (size_t)(N+1)*4;
  int* cursor = (int*)p;    p += (size_t)N*4;
  int* csr    = (int*)p;    p += (size_t)tot*4;

  const int gE = (tot + 255) / 256;
  const int gN4 = (N + 3) / 4;
  const int gG = ((N + 63) / 64) * 2;

  // ---- CSR build (shared by both layers) ----
  k_zero <<<(N+255)/256,256,0,stream>>>(deg, N);
  k_count<<<gE,256,0,stream>>>(ei, E, N, deg);
  k_scan <<<1,256,0,stream>>>(deg, rowptr, cursor, N);
  k_fill <<<gE,256,0,stream>>>(ei, E, N, cursor, csr);

  // ---- layer 1 (concat heads) ----
  k_gemm_att<128><<<gG,256,0,stream>>>(x, W1, att_s1, att_d1, h, asrc, adst, N);
  k_node_agg1<<<gN4,256,0,stream>>>(rowptr, csr, asrc, adst, h, b1, agg1, N);

  // ---- layer 2 (head mean) ----
  k_gemm_att<256><<<gG,256,0,stream>>>(agg1, W2, att_s2, att_d2, h, asrc, adst, N);
  k_node_agg2<<<gN4,256,0,stream>>>(rowptr, csr, asrc, adst, h, b2, agg2, N);

  // ---- feed-forward head ----
  k_ff<<<(N+255)/256,256,0,stream>>>(agg2, ff1w, ff1b, ff2w, ff2b, out, N);
}